// Round 1
// baseline (754.864 us; speedup 1.0000x reference)
//
#include <hip/hip_runtime.h>
#include <cstdint>
#include <cstddef>

// ---------- types / helpers ----------
typedef __bf16 bf16x8 __attribute__((ext_vector_type(8)));
typedef float  floatx4 __attribute__((ext_vector_type(4)));
typedef unsigned short ushort8 __attribute__((ext_vector_type(8)));

__device__ __forceinline__ float bf2f(unsigned short u) {
    union { unsigned int u32; float f; } x; x.u32 = ((unsigned int)u) << 16; return x.f;
}
__device__ __forceinline__ unsigned short f2bf(float f) {
    union { float f; unsigned int u; } x; x.f = f;
    unsigned int u = x.u;
    unsigned int r = (u + 0x7fffu + ((u >> 16) & 1u)) >> 16;   // RNE
    return (unsigned short)r;
}

#define GLOBAL_U32 const __attribute__((address_space(1))) unsigned int*
#define LDS_U32 __attribute__((address_space(3))) unsigned int*
__device__ __forceinline__ void async_cp16(const void* g, void* l) {
    __builtin_amdgcn_global_load_lds((GLOBAL_U32)g, (LDS_U32)l, 16, 0, 0);
}

// ---------- conv1: x[256,1,28,28] * w[256,1,9,9] -> h1t bf16 NHWC [b][20][20][256] ----------
__global__ __launch_bounds__(256) void conv1_k(const float* __restrict__ x,
                                               const float* __restrict__ w,
                                               const float* __restrict__ bias,
                                               unsigned short* __restrict__ h1t) {
    const int b = blockIdx.x, t = threadIdx.x;
    __shared__ float xs[784];
    for (int idx = t; idx < 784; idx += 256) xs[idx] = x[b * 784 + idx];
    __syncthreads();
    const float* wr = w + t * 81;   // thread t = output channel t
    const float bv = bias[t];
    for (int oh = 0; oh < 20; ++oh) {
        float acc[20];
#pragma unroll
        for (int ow = 0; ow < 20; ++ow) acc[ow] = bv;
#pragma unroll
        for (int kh = 0; kh < 9; ++kh) {
            float xr[28];
            const float* xrow = &xs[(oh + kh) * 28];
#pragma unroll
            for (int q = 0; q < 7; ++q) *(float4*)&xr[q * 4] = *(const float4*)&xrow[q * 4];
#pragma unroll
            for (int kw = 0; kw < 9; ++kw) {
                const float wv = wr[kh * 9 + kw];
#pragma unroll
                for (int ow = 0; ow < 20; ++ow) acc[ow] = fmaf(xr[ow + kw], wv, acc[ow]);
            }
        }
        unsigned short* orow = h1t + (size_t)((b * 20 + oh) * 20) * 256 + t;
#pragma unroll
        for (int ow = 0; ow < 20; ++ow) orow[ow * 256] = f2bf(acc[ow]);
    }
}

// ---------- w2 transform: OIHW fp32 [oc][ic][81] -> bf16 [oc][tap*256+ic] ----------
__global__ __launch_bounds__(256) void w2t_k(const float* __restrict__ w2,
                                             unsigned short* __restrict__ w2t) {
    const int oc = blockIdx.x >> 1, half = blockIdx.x & 1, t = threadIdx.x;
    __shared__ float ws[10368];                       // 128 ic * 81 taps
    const float* src = w2 + (size_t)oc * 20736 + half * 128 * 81;
    for (int idx = t; idx < 10368; idx += 256) ws[idx] = src[idx];
    __syncthreads();
    unsigned short* dst = w2t + (size_t)oc * 20736 + half * 128;
    for (int idx = t; idx < 10368; idx += 256) {
        const int tap = idx >> 7, icl = idx & 127;
        dst[tap * 256 + icl] = f2bf(ws[icl * 81 + tap]);
    }
}

// ---------- conv2 as implicit GEMM, bf16 MFMA, split-K x4 ----------
__device__ __forceinline__ int c2_rowbase(int m) {
    const int b = m / 36, sp = m % 36;
    const int oh = sp / 6, ow = sp % 6;
    return (b * 400 + oh * 40 + ow * 2) * 256;        // element offset into h1t
}

__global__ __launch_bounds__(256) void conv2_k(const unsigned short* __restrict__ h1t,
                                               const unsigned short* __restrict__ w2t,
                                               float* __restrict__ part) {
    const int t = threadIdx.x;
    const int bx = blockIdx.x;                        // 0..1 oc-tile
    const int by = blockIdx.y;                        // 0..71 m-tile
    const int z  = blockIdx.z;                        // 0..3 k-split
    __shared__ unsigned short At[128 * 32];
    __shared__ unsigned short Bt[128 * 32];

    const int r0 = t >> 2, sub = t & 3;
    const int ra0 = c2_rowbase(by * 128 + r0) + sub * 8;
    const int ra1 = c2_rowbase(by * 128 + r0 + 64) + sub * 8;
    const int oc0 = bx * 128;
    const int bb0 = (oc0 + r0) * 20736 + sub * 8;
    const int bb1 = (oc0 + r0 + 64) * 20736 + sub * 8;

    const int lane = t & 63, l15 = lane & 15, quad = lane >> 4;
    const int wave = t >> 6;
    const int wm = (wave & 1) * 64, wn = (wave >> 1) * 64;

    floatx4 acc[4][4];
#pragma unroll
    for (int i = 0; i < 4; ++i)
#pragma unroll
        for (int j = 0; j < 4; ++j) acc[i][j] = (floatx4){0.f, 0.f, 0.f, 0.f};

    const int kc0 = z * 162, kc1 = kc0 + 162;
    for (int kc = kc0; kc < kc1; ++kc) {
        const int tap = kc >> 3;
        const int kh = tap / 9, kw = tap % 9;
        const int ic0 = (kc & 7) << 5;
        const int aoff = (kh * 20 + kw) * 256 + ic0;
        const int k0 = kc << 5;
        __syncthreads();
        async_cp16(h1t + ra0 + aoff, At + t * 8);
        async_cp16(h1t + ra1 + aoff, At + (t + 256) * 8);
        async_cp16(w2t + bb0 + k0, Bt + t * 8);
        async_cp16(w2t + bb1 + k0, Bt + (t + 256) * 8);
        __syncthreads();
        bf16x8 aF[4], bF[4];
#pragma unroll
        for (int mt = 0; mt < 4; ++mt)
            aF[mt] = *(const bf16x8*)(At + (wm + mt * 16 + l15) * 32 + quad * 8);
#pragma unroll
        for (int nt = 0; nt < 4; ++nt)
            bF[nt] = *(const bf16x8*)(Bt + (wn + nt * 16 + l15) * 32 + quad * 8);
#pragma unroll
        for (int mt = 0; mt < 4; ++mt)
#pragma unroll
            for (int nt = 0; nt < 4; ++nt)
                acc[mt][nt] = __builtin_amdgcn_mfma_f32_16x16x32_bf16(aF[mt], bF[nt], acc[mt][nt], 0, 0, 0);
    }

    float* outp = part + (size_t)z * 9216 * 256;
#pragma unroll
    for (int mt = 0; mt < 4; ++mt)
#pragma unroll
        for (int nt = 0; nt < 4; ++nt) {
            const int n = oc0 + wn + nt * 16 + l15;
#pragma unroll
            for (int r = 0; r < 4; ++r) {
                const int m = by * 128 + wm + mt * 16 + quad * 4 + r;
                outp[(size_t)m * 256 + n] = acc[mt][nt][r];
            }
        }
}

// ---------- reduce split-K + bias + squash(axis=w) -> u[b][1152][8] fp32 ----------
__global__ __launch_bounds__(256) void squash_u_k(const float* __restrict__ part,
                                                  const float* __restrict__ bias,
                                                  float* __restrict__ u) {
    const int b = blockIdx.x, t = threadIdx.x;
    __shared__ float hs[9216];
    const size_t base = (size_t)b * 9216;
    for (int idx = t; idx < 9216; idx += 256) {
        float v = part[base + idx] + part[2359296 + base + idx] +
                  part[2 * 2359296 + base + idx] + part[3 * 2359296 + base + idx];
        hs[idx] = v + bias[idx & 255];
    }
    __syncthreads();
    for (int g = t; g < 1536; g += 256) {            // groups (c, oh), squash over ow(6)
        const int c = g / 6, oh = g % 6;
        float s[6], sq = 0.f;
#pragma unroll
        for (int ow = 0; ow < 6; ++ow) { s[ow] = hs[(oh * 6 + ow) * 256 + c]; sq = fmaf(s[ow], s[ow], sq); }
        const float norm = sqrtf(sq);
        const float f = (sq / (1.0f + sq)) / (norm + 1e-7f);
        float* up = u + base + c * 36 + oh * 6;
#pragma unroll
        for (int ow = 0; ow < 6; ++ow) up[ow] = s[ow] * f;
    }
}

// ---------- u_hat[i][b][o*16+d] bf16 = sum_e W[o,i,d,e]*u[b,i,e] ----------
__global__ __launch_bounds__(256) void uhat_k(const float* __restrict__ Wc,
                                              const float* __restrict__ u,
                                              unsigned short* __restrict__ uhat) {
    const int i = blockIdx.x, t = threadIdx.x;       // t = b
    __shared__ float Wl[1280];                       // [o][d*8+e]
    for (int idx = t; idx < 1280; idx += 256) {
        const int o = idx >> 7, r = idx & 127;
        Wl[idx] = Wc[((size_t)o * 1152 + i) * 128 + r];
    }
    float ur[8];
    *(float4*)&ur[0] = *(const float4*)(u + (size_t)t * 9216 + i * 8);
    *(float4*)&ur[4] = *(const float4*)(u + (size_t)t * 9216 + i * 8 + 4);
    __syncthreads();
    unsigned short* dst = uhat + ((size_t)i * 256 + t) * 160;
#pragma unroll 1
    for (int o = 0; o < 10; ++o) {
        ushort8 v0, v1;
#pragma unroll
        for (int d = 0; d < 16; ++d) {
            const float* wp = &Wl[o * 128 + d * 8];
            float a = 0.f;
#pragma unroll
            for (int e = 0; e < 8; ++e) a = fmaf(wp[e], ur[e], a);
            if (d < 8) v0[d] = f2bf(a); else v1[d - 8] = f2bf(a);
        }
        *(ushort8*)(dst + o * 16) = v0;
        *(ushort8*)(dst + o * 16 + 8) = v1;
    }
}

// ---------- dynamic routing (3 iters) + lengths + argmax + masked v ----------
__global__ __launch_bounds__(256) void routing_k(const unsigned short* __restrict__ uhat,
                                                 float* __restrict__ out_len,
                                                 int* __restrict__ sel,
                                                 float* __restrict__ vsel) {
    const int b = blockIdx.x, t = threadIdx.x;
    __shared__ float c_s[11520];                     // c[i][o]
    __shared__ float s_s[160], v_s[160], f_s[10], len_s[10];
    __shared__ int sel_s;
    float bl[5][10];                                 // b_logits for i = t + 256*j
#pragma unroll
    for (int j = 0; j < 5; ++j)
#pragma unroll
        for (int o = 0; o < 10; ++o) bl[j][o] = 0.f;

    const int o_t = t >> 4;
    // ---- iter 0: c uniform = 0.1 ----
    float sacc = 0.f;
    if (t < 160) {
        const unsigned short* p = uhat + (size_t)b * 160 + t;
        for (int i = 0; i < 1152; i += 4) {
            sacc += bf2f(p[(size_t)(i + 0) * 40960]);
            sacc += bf2f(p[(size_t)(i + 1) * 40960]);
            sacc += bf2f(p[(size_t)(i + 2) * 40960]);
            sacc += bf2f(p[(size_t)(i + 3) * 40960]);
        }
        sacc *= 0.1f;
    }
    if (t < 160) s_s[t] = sacc;
    __syncthreads();
    if (t < 10) {
        float sq = 0.f;
#pragma unroll
        for (int d = 0; d < 16; ++d) { const float xx = s_s[t * 16 + d]; sq = fmaf(xx, xx, sq); }
        const float norm = sqrtf(sq);
        f_s[t] = (sq / (1.f + sq)) / (norm + 1e-7f);
    }
    __syncthreads();
    if (t < 160) v_s[t] = s_s[t] * f_s[o_t];
    __syncthreads();

    for (int iter = 1; iter < 3; ++iter) {
        // phase 1: bl += v.u_hat ; softmax over o -> c_s
        for (int j = 0, i = t; i < 1152; ++j, i += 256) {
            const unsigned short* row = uhat + ((size_t)i * 256 + b) * 160;
            float mx = -1e30f;
#pragma unroll 1
            for (int o = 0; o < 10; ++o) {
                const ushort8 ua = *(const ushort8*)(row + o * 16);
                const ushort8 ub = *(const ushort8*)(row + o * 16 + 8);
                float dot = 0.f;
#pragma unroll
                for (int d = 0; d < 8; ++d) dot = fmaf(bf2f(ua[d]), v_s[o * 16 + d], dot);
#pragma unroll
                for (int d = 0; d < 8; ++d) dot = fmaf(bf2f(ub[d]), v_s[o * 16 + 8 + d], dot);
                bl[j][o] += dot;
                mx = fmaxf(mx, bl[j][o]);
            }
            float ex[10], sum = 0.f;
#pragma unroll
            for (int o = 0; o < 10; ++o) { ex[o] = expf(bl[j][o] - mx); sum += ex[o]; }
            const float inv = 1.f / sum;
#pragma unroll
            for (int o = 0; o < 10; ++o) c_s[i * 10 + o] = ex[o] * inv;
        }
        __syncthreads();
        // phase 2: s[o,d] = sum_i c[i,o] * u_hat[i,o,d]
        sacc = 0.f;
        if (t < 160) {
            const unsigned short* p = uhat + (size_t)b * 160 + t;
            for (int i = 0; i < 1152; i += 2) {
                sacc = fmaf(c_s[i * 10 + o_t], bf2f(p[(size_t)i * 40960]), sacc);
                sacc = fmaf(c_s[(i + 1) * 10 + o_t], bf2f(p[(size_t)(i + 1) * 40960]), sacc);
            }
        }
        if (t < 160) s_s[t] = sacc;
        __syncthreads();
        if (t < 10) {
            float sq = 0.f;
#pragma unroll
            for (int d = 0; d < 16; ++d) { const float xx = s_s[t * 16 + d]; sq = fmaf(xx, xx, sq); }
            const float norm = sqrtf(sq);
            f_s[t] = (sq / (1.f + sq)) / (norm + 1e-7f);
        }
        __syncthreads();
        if (t < 160) v_s[t] = s_s[t] * f_s[o_t];
        __syncthreads();
    }

    if (t < 10) {
        float sq = 0.f;
#pragma unroll
        for (int d = 0; d < 16; ++d) { const float xx = v_s[t * 16 + d]; sq = fmaf(xx, xx, sq); }
        len_s[t] = sqrtf(sq);
        out_len[b * 10 + t] = len_s[t];
    }
    __syncthreads();
    if (t == 0) {
        float best = len_s[0]; int bi = 0;
        for (int o = 1; o < 10; ++o) if (len_s[o] > best) { best = len_s[o]; bi = o; }
        sel_s = bi; sel[b] = bi;
    }
    __syncthreads();
    if (t < 16) vsel[b * 16 + t] = v_s[sel_s * 16 + t];
}

// ---------- decoder layer 1 (gathered 16 rows) ----------
__global__ __launch_bounds__(256) void dec1_k(const float* __restrict__ w1,
                                              const float* __restrict__ b1,
                                              const float* __restrict__ vsel,
                                              const int* __restrict__ sel,
                                              float* __restrict__ h1d) {
    const int bx = blockIdx.x;
    const int b = bx >> 1;
    const int col = ((bx & 1) << 8) + threadIdx.x;
    const int s = sel[b];
    float acc = b1[col];
    const float* wrow = w1 + (size_t)(s * 16) * 512 + col;
#pragma unroll
    for (int j = 0; j < 16; ++j) acc = fmaf(vsel[b * 16 + j], wrow[j * 512], acc);
    h1d[(size_t)b * 512 + col] = fmaxf(acc, 0.f);
}

// ---------- generic small fp32 GEMM + act (M=256 fixed) ----------
template <int ACT>
__global__ __launch_bounds__(256) void mlp_k(const float* __restrict__ A,
                                             const float* __restrict__ Bm,
                                             const float* __restrict__ bias,
                                             float* __restrict__ C, int N, int K) {
    __shared__ float As[64 * 16];
    __shared__ float Bs[16 * 64];
    const int t = threadIdx.x;
    const int tx = t & 15, ty = t >> 4;
    const int m0 = blockIdx.y * 64, n0 = blockIdx.x * 64;
    float acc[4][4] = {};
    const int arow = t >> 2, ac4 = (t & 3) * 4;
    const int brow = t >> 4, bc4 = (t & 15) * 4;
    for (int k0 = 0; k0 < K; k0 += 16) {
        __syncthreads();
        *(float4*)&As[arow * 16 + ac4] = *(const float4*)&A[(size_t)(m0 + arow) * K + k0 + ac4];
        float4 bv = {0.f, 0.f, 0.f, 0.f};
        const int bn = n0 + bc4;
        if (bn + 3 < N) bv = *(const float4*)&Bm[(size_t)(k0 + brow) * N + bn];
        *(float4*)&Bs[brow * 64 + bc4] = bv;
        __syncthreads();
#pragma unroll
        for (int k = 0; k < 16; ++k) {
            float av[4], bvv[4];
#pragma unroll
            for (int r = 0; r < 4; ++r) av[r] = As[(ty * 4 + r) * 16 + k];
#pragma unroll
            for (int c = 0; c < 4; ++c) bvv[c] = Bs[k * 64 + tx * 4 + c];
#pragma unroll
            for (int r = 0; r < 4; ++r)
#pragma unroll
                for (int c = 0; c < 4; ++c) acc[r][c] = fmaf(av[r], bvv[c], acc[r][c]);
        }
    }
#pragma unroll
    for (int r = 0; r < 4; ++r) {
        const int m = m0 + ty * 4 + r;
#pragma unroll
        for (int c = 0; c < 4; ++c) {
            const int n = n0 + tx * 4 + c;
            if (n < N) {
                float v = acc[r][c] + bias[n];
                if (ACT == 0) v = fmaxf(v, 0.f);
                else v = 1.f / (1.f + expf(-v));
                C[(size_t)m * N + n] = v;
            }
        }
    }
}

// ---------- launcher ----------
extern "C" void kernel_launch(void* const* d_in, const int* in_sizes, int n_in,
                              void* d_out, int out_size, void* d_ws, size_t ws_size,
                              hipStream_t stream) {
    const float* x   = (const float*)d_in[0];
    const float* w1  = (const float*)d_in[1];
    const float* b1  = (const float*)d_in[2];
    const float* w2  = (const float*)d_in[3];
    const float* b2  = (const float*)d_in[4];
    const float* Wc  = (const float*)d_in[5];
    const float* dw1 = (const float*)d_in[6];
    const float* db1 = (const float*)d_in[7];
    const float* dw2 = (const float*)d_in[8];
    const float* db2 = (const float*)d_in[9];
    const float* dw3 = (const float*)d_in[10];
    const float* db3 = (const float*)d_in[11];
    float* out = (float*)d_out;

    char* ws = (char*)d_ws;
    // region A: staging (dead after squash_u_k), then reused by UHAT
    unsigned short* H1T  = (unsigned short*)(ws + 0);          // 52,428,800 B
    unsigned short* W2T  = (unsigned short*)(ws + 52428800);   // 10,616,832 B
    float*          PART = (float*)(ws + 63045632);            // 37,748,736 B
    unsigned short* UHAT = (unsigned short*)(ws + 0);          // 94,371,840 B (aliases region A)
    float* U    = (float*)(ws + 100794368);                    //  9,437,184 B
    int*   SEL  = (int*)(ws + 110231552);
    float* VSEL = (float*)(ws + 110232576);
    float* H1D  = (float*)(ws + 110248960);
    float* H2D  = (float*)(ws + 110773248);                    // end 111,821,824

    conv1_k<<<256, 256, 0, stream>>>(x, w1, b1, H1T);
    w2t_k<<<512, 256, 0, stream>>>(w2, W2T);
    conv2_k<<<dim3(2, 72, 4), 256, 0, stream>>>(H1T, W2T, PART);
    squash_u_k<<<256, 256, 0, stream>>>(PART, b2, U);
    uhat_k<<<1152, 256, 0, stream>>>(Wc, U, UHAT);
    routing_k<<<256, 256, 0, stream>>>(UHAT, out, SEL, VSEL);
    dec1_k<<<512, 256, 0, stream>>>(dw1, db1, VSEL, SEL, H1D);
    mlp_k<0><<<dim3(16, 4), 256, 0, stream>>>(H1D, dw2, db2, H2D, 1024, 512);
    mlp_k<1><<<dim3(13, 4), 256, 0, stream>>>(H2D, dw3, db3, out + 2560, 784, 1024);
}

// Round 2
// 736.688 us; speedup vs baseline: 1.0247x; 1.0247x over previous
//
#include <hip/hip_runtime.h>
#include <cstdint>
#include <cstddef>

// ---------- types / helpers ----------
typedef __bf16 bf16x8 __attribute__((ext_vector_type(8)));
typedef float  floatx4 __attribute__((ext_vector_type(4)));
typedef unsigned short ushort8 __attribute__((ext_vector_type(8)));

__device__ __forceinline__ float bf2f(unsigned short u) {
    union { unsigned int u32; float f; } x; x.u32 = ((unsigned int)u) << 16; return x.f;
}
__device__ __forceinline__ float bflo(unsigned int u) {
    union { unsigned int u32; float f; } x; x.u32 = u << 16; return x.f;
}
__device__ __forceinline__ float bfhi(unsigned int u) {
    union { unsigned int u32; float f; } x; x.u32 = u & 0xffff0000u; return x.f;
}
__device__ __forceinline__ unsigned short f2bf(float f) {
    union { float f; unsigned int u; } x; x.f = f;
    unsigned int u = x.u;
    unsigned int r = (u + 0x7fffu + ((u >> 16) & 1u)) >> 16;   // RNE
    return (unsigned short)r;
}

#define GLOBAL_U32 const __attribute__((address_space(1))) unsigned int*
#define LDS_U32 __attribute__((address_space(3))) unsigned int*
__device__ __forceinline__ void async_cp16(const void* g, void* l) {
    __builtin_amdgcn_global_load_lds((GLOBAL_U32)g, (LDS_U32)l, 16, 0, 0);
}

// ---------- conv1: x[256,1,28,28] * w[256,1,9,9] -> h1t bf16 NHWC [b][20][20][256] ----------
__global__ __launch_bounds__(256) void conv1_k(const float* __restrict__ x,
                                               const float* __restrict__ w,
                                               const float* __restrict__ bias,
                                               unsigned short* __restrict__ h1t) {
    const int b = blockIdx.x, t = threadIdx.x;
    __shared__ float xs[784];
    for (int idx = t; idx < 784; idx += 256) xs[idx] = x[b * 784 + idx];
    __syncthreads();
    const float* wr = w + t * 81;   // thread t = output channel t
    const float bv = bias[t];
    for (int oh = 0; oh < 20; ++oh) {
        float acc[20];
#pragma unroll
        for (int ow = 0; ow < 20; ++ow) acc[ow] = bv;
#pragma unroll
        for (int kh = 0; kh < 9; ++kh) {
            float xr[28];
            const float* xrow = &xs[(oh + kh) * 28];
#pragma unroll
            for (int q = 0; q < 7; ++q) *(float4*)&xr[q * 4] = *(const float4*)&xrow[q * 4];
#pragma unroll
            for (int kw = 0; kw < 9; ++kw) {
                const float wv = wr[kh * 9 + kw];
#pragma unroll
                for (int ow = 0; ow < 20; ++ow) acc[ow] = fmaf(xr[ow + kw], wv, acc[ow]);
            }
        }
        unsigned short* orow = h1t + (size_t)((b * 20 + oh) * 20) * 256 + t;
#pragma unroll
        for (int ow = 0; ow < 20; ++ow) orow[ow * 256] = f2bf(acc[ow]);
    }
}

// ---------- w2 transform: OIHW fp32 [oc][ic][81] -> bf16 [oc][tap*256+ic] ----------
__global__ __launch_bounds__(256) void w2t_k(const float* __restrict__ w2,
                                             unsigned short* __restrict__ w2t) {
    const int oc = blockIdx.x >> 1, half = blockIdx.x & 1, t = threadIdx.x;
    __shared__ float ws[10368];                       // 128 ic * 81 taps
    const float* src = w2 + (size_t)oc * 20736 + half * 128 * 81;
    for (int idx = t; idx < 10368; idx += 256) ws[idx] = src[idx];
    __syncthreads();
    unsigned short* dst = w2t + (size_t)oc * 20736 + half * 128;
    for (int idx = t; idx < 10368; idx += 256) {
        const int tap = idx >> 7, icl = idx & 127;
        dst[tap * 256 + icl] = f2bf(ws[icl * 81 + tap]);
    }
}

// ---------- conv2 as implicit GEMM, bf16 MFMA, split-K x4 ----------
__device__ __forceinline__ int c2_rowbase(int m) {
    const int b = m / 36, sp = m % 36;
    const int oh = sp / 6, ow = sp % 6;
    return (b * 400 + oh * 40 + ow * 2) * 256;        // element offset into h1t
}

__global__ __launch_bounds__(256) void conv2_k(const unsigned short* __restrict__ h1t,
                                               const unsigned short* __restrict__ w2t,
                                               float* __restrict__ part) {
    const int t = threadIdx.x;
    const int bx = blockIdx.x;                        // 0..1 oc-tile
    const int by = blockIdx.y;                        // 0..71 m-tile
    const int z  = blockIdx.z;                        // 0..3 k-split
    __shared__ unsigned short At[128 * 32];
    __shared__ unsigned short Bt[128 * 32];

    const int r0 = t >> 2, sub = t & 3;
    const int ra0 = c2_rowbase(by * 128 + r0) + sub * 8;
    const int ra1 = c2_rowbase(by * 128 + r0 + 64) + sub * 8;
    const int oc0 = bx * 128;
    const int bb0 = (oc0 + r0) * 20736 + sub * 8;
    const int bb1 = (oc0 + r0 + 64) * 20736 + sub * 8;

    const int lane = t & 63, l15 = lane & 15, quad = lane >> 4;
    const int wave = t >> 6;
    const int wm = (wave & 1) * 64, wn = (wave >> 1) * 64;

    floatx4 acc[4][4];
#pragma unroll
    for (int i = 0; i < 4; ++i)
#pragma unroll
        for (int j = 0; j < 4; ++j) acc[i][j] = (floatx4){0.f, 0.f, 0.f, 0.f};

    const int kc0 = z * 162, kc1 = kc0 + 162;
    for (int kc = kc0; kc < kc1; ++kc) {
        const int tap = kc >> 3;
        const int kh = tap / 9, kw = tap % 9;
        const int ic0 = (kc & 7) << 5;
        const int aoff = (kh * 20 + kw) * 256 + ic0;
        const int k0 = kc << 5;
        __syncthreads();
        async_cp16(h1t + ra0 + aoff, At + t * 8);
        async_cp16(h1t + ra1 + aoff, At + (t + 256) * 8);
        async_cp16(w2t + bb0 + k0, Bt + t * 8);
        async_cp16(w2t + bb1 + k0, Bt + (t + 256) * 8);
        __syncthreads();
        bf16x8 aF[4], bF[4];
#pragma unroll
        for (int mt = 0; mt < 4; ++mt)
            aF[mt] = *(const bf16x8*)(At + (wm + mt * 16 + l15) * 32 + quad * 8);
#pragma unroll
        for (int nt = 0; nt < 4; ++nt)
            bF[nt] = *(const bf16x8*)(Bt + (wn + nt * 16 + l15) * 32 + quad * 8);
#pragma unroll
        for (int mt = 0; mt < 4; ++mt)
#pragma unroll
            for (int nt = 0; nt < 4; ++nt)
                acc[mt][nt] = __builtin_amdgcn_mfma_f32_16x16x32_bf16(aF[mt], bF[nt], acc[mt][nt], 0, 0, 0);
    }

    float* outp = part + (size_t)z * 9216 * 256;
#pragma unroll
    for (int mt = 0; mt < 4; ++mt)
#pragma unroll
        for (int nt = 0; nt < 4; ++nt) {
            const int n = oc0 + wn + nt * 16 + l15;
#pragma unroll
            for (int r = 0; r < 4; ++r) {
                const int m = by * 128 + wm + mt * 16 + quad * 4 + r;
                outp[(size_t)m * 256 + n] = acc[mt][nt][r];
            }
        }
}

// ---------- reduce split-K + bias + squash(axis=w) -> u[b][1152][8] fp32 ----------
__global__ __launch_bounds__(256) void squash_u_k(const float* __restrict__ part,
                                                  const float* __restrict__ bias,
                                                  float* __restrict__ u) {
    const int b = blockIdx.x, t = threadIdx.x;
    __shared__ float hs[9216];
    const size_t base = (size_t)b * 9216;
    for (int idx = t; idx < 9216; idx += 256) {
        float v = part[base + idx] + part[2359296 + base + idx] +
                  part[2 * 2359296 + base + idx] + part[3 * 2359296 + base + idx];
        hs[idx] = v + bias[idx & 255];
    }
    __syncthreads();
    for (int g = t; g < 1536; g += 256) {            // groups (c, oh), squash over ow(6)
        const int c = g / 6, oh = g % 6;
        float s[6], sq = 0.f;
#pragma unroll
        for (int ow = 0; ow < 6; ++ow) { s[ow] = hs[(oh * 6 + ow) * 256 + c]; sq = fmaf(s[ow], s[ow], sq); }
        const float norm = sqrtf(sq);
        const float f = (sq / (1.0f + sq)) / (norm + 1e-7f);
        float* up = u + base + c * 36 + oh * 6;
#pragma unroll
        for (int ow = 0; ow < 6; ++ow) up[ow] = s[ow] * f;
    }
}

// ---------- u_hat[b][i][o*16+d] bf16 = sum_e W[o,i,d,e]*u[b,i,e] ----------
// block = i (1152); thread t = b. LDS transpose in two 128-b halves so global
// stores are 16B-coalesced contiguous rows.
__global__ __launch_bounds__(256) void uhat_k(const float* __restrict__ Wc,
                                              const float* __restrict__ u,
                                              unsigned short* __restrict__ uhat) {
    const int i = blockIdx.x, t = threadIdx.x;       // t = b
    __shared__ float Wl[1280];                       // [o][d*8+e]
    __shared__ unsigned short Ul[128 * 168];         // padded transpose buffer (43 KB)
    for (int idx = t; idx < 1280; idx += 256) {
        const int o = idx >> 7, r = idx & 127;
        Wl[idx] = Wc[((size_t)o * 1152 + i) * 128 + r];
    }
    float ur[8];
    *(float4*)&ur[0] = *(const float4*)(u + (size_t)t * 9216 + i * 8);
    *(float4*)&ur[4] = *(const float4*)(u + (size_t)t * 9216 + i * 8 + 4);
    __syncthreads();
    unsigned short val[160];
#pragma unroll 1
    for (int o = 0; o < 10; ++o) {
#pragma unroll
        for (int d = 0; d < 16; ++d) {
            const float* wp = &Wl[o * 128 + d * 8];
            float a = 0.f;
#pragma unroll
            for (int e = 0; e < 8; ++e) a = fmaf(wp[e], ur[e], a);
            val[o * 16 + d] = f2bf(a);
        }
    }
#pragma unroll 1
    for (int h = 0; h < 2; ++h) {
        __syncthreads();
        if ((t >> 7) == h) {
            unsigned short* row = &Ul[(t & 127) * 168];
#pragma unroll
            for (int q = 0; q < 20; ++q) *(ushort8*)(row + q * 8) = *(const ushort8*)(val + q * 8);
        }
        __syncthreads();
        // drain 128 rows x 320B, coalesced 16B stores
        for (int idx = t; idx < 2560; idx += 256) {
            const int r = idx / 20, q = idx % 20;
            const int b = h * 128 + r;
            *(ushort8*)(uhat + ((size_t)b * 1152 + i) * 160 + q * 8) =
                *(const ushort8*)(&Ul[r * 168 + q * 8]);
        }
    }
}

// ---------- routing iteration 0: S0[b][160] = 0.1 * sum_i u_hat ----------
__global__ __launch_bounds__(128) void route_iter0_k(const unsigned int* __restrict__ uhat32,
                                                     float* __restrict__ S0) {
    const int b = blockIdx.x, i0 = blockIdx.y * 128, t = threadIdx.x;
    if (t >= 80) return;
    const unsigned int* p = uhat32 + ((size_t)b * 1152 + i0) * 80 + t;
    float ax = 0.f, ay = 0.f;
#pragma unroll 8
    for (int i = 0; i < 128; ++i) {
        const unsigned int uu = p[i * 80];
        ax += bflo(uu);
        ay += bfhi(uu);
    }
    atomicAdd(&S0[b * 160 + 2 * t], 0.1f * ax);
    atomicAdd(&S0[b * 160 + 2 * t + 1], 0.1f * ay);
}

// ---------- fused routing iteration: logit update + softmax + weighted sum ----------
// grid (256 b, 9 chunks), 256 threads. u_hat slab staged once into LDS,
// used by both phases. c never leaves LDS. S accumulated via fp32 atomics.
template <int ITER>
__global__ __launch_bounds__(256) void route_iter_k(const unsigned short* __restrict__ uhat,
                                                    const float* __restrict__ V,
                                                    float* __restrict__ BL,
                                                    float* __restrict__ S) {
    const int b = blockIdx.x, i0 = blockIdx.y * 128, t = threadIdx.x;
    __shared__ __align__(16) unsigned short Ul[128 * 160];   // 40960 B
    __shared__ float cT[10 * 132];                           // padded: bank-conflict-free broadcast
    __shared__ float dots[128 * 10];

    const char* gsrc = (const char*)(uhat + ((size_t)b * 1152 + i0) * 160);
#pragma unroll
    for (int rep = 0; rep < 10; ++rep)
        async_cp16(gsrc + rep * 4096 + t * 16, (char*)Ul + rep * 4096 + t * 16);

    float2 vt = make_float2(0.f, 0.f);
    if (t < 80) vt = *(const float2*)(V + b * 160 + 2 * t);
    const unsigned int* Ul32 = (const unsigned int*)Ul;
    const int o8 = t >> 3;                                   // o for t<80 (pair layout)
    __syncthreads();

    // p1a: dots[i][o] = sum_d u_hat[i,o,d] * v[o,d]   (paired-bf16 + width-8 shuffle)
    if (t < 80) {
#pragma unroll 4
        for (int i = 0; i < 128; ++i) {
            const unsigned int uu = Ul32[i * 80 + t];
            float pu = bflo(uu) * vt.x + bfhi(uu) * vt.y;
            pu += __shfl_xor(pu, 1, 8);
            pu += __shfl_xor(pu, 2, 8);
            pu += __shfl_xor(pu, 4, 8);
            if ((t & 7) == 0) dots[i * 10 + o8] = pu;
        }
    }
    __syncthreads();

    // p1b: per-i logits + softmax -> cT[o][i]
    if (t < 128) {
        float bl[10];
#pragma unroll
        for (int o = 0; o < 10; ++o) bl[o] = dots[t * 10 + o];
        if (ITER == 2) {
#pragma unroll
            for (int o = 0; o < 10; ++o) bl[o] += BL[(size_t)b * 11520 + o * 1152 + i0 + t];
        } else {
#pragma unroll
            for (int o = 0; o < 10; ++o) BL[(size_t)b * 11520 + o * 1152 + i0 + t] = bl[o];
        }
        float mx = bl[0];
#pragma unroll
        for (int o = 1; o < 10; ++o) mx = fmaxf(mx, bl[o]);
        float ex[10], sum = 0.f;
#pragma unroll
        for (int o = 0; o < 10; ++o) { ex[o] = expf(bl[o] - mx); sum += ex[o]; }
        const float inv = 1.f / sum;
#pragma unroll
        for (int o = 0; o < 10; ++o) cT[o * 132 + t] = ex[o] * inv;
    }
    __syncthreads();

    // p2: S[b][160] += sum_i c[i][o] * u_hat[i][od]
    if (t < 80) {
        float ax = 0.f, ay = 0.f;
#pragma unroll 4
        for (int i = 0; i < 128; ++i) {
            const float c = cT[o8 * 132 + i];
            const unsigned int uu = Ul32[i * 80 + t];
            ax = fmaf(c, bflo(uu), ax);
            ay = fmaf(c, bfhi(uu), ay);
        }
        atomicAdd(&S[b * 160 + 2 * t], ax);
        atomicAdd(&S[b * 160 + 2 * t + 1], ay);
    }
}

// ---------- squash S -> V (+ final: lengths, argmax, vsel) ----------
template <int FINAL>
__global__ __launch_bounds__(160) void squash_v_k(const float* __restrict__ S,
                                                  float* __restrict__ V,
                                                  float* __restrict__ out_len,
                                                  int* __restrict__ sel,
                                                  float* __restrict__ vsel) {
    const int b = blockIdx.x, t = threadIdx.x, o = t >> 4;
    __shared__ float len_s[10];
    __shared__ int sel_s;
    const float x = S[b * 160 + t];
    float sq = x * x;
    sq += __shfl_xor(sq, 1, 16);
    sq += __shfl_xor(sq, 2, 16);
    sq += __shfl_xor(sq, 4, 16);
    sq += __shfl_xor(sq, 8, 16);
    const float norm = sqrtf(sq);
    const float f = (sq / (1.f + sq)) / (norm + 1e-7f);
    V[b * 160 + t] = x * f;
    if (FINAL) {
        if ((t & 15) == 0) {
            const float len = f * norm;
            len_s[o] = len;
            out_len[b * 10 + o] = len;
        }
        __syncthreads();
        if (t == 0) {
            float best = len_s[0]; int bi = 0;
            for (int oo = 1; oo < 10; ++oo) if (len_s[oo] > best) { best = len_s[oo]; bi = oo; }
            sel_s = bi; sel[b] = bi;
        }
        __syncthreads();
        if (t < 16) vsel[b * 16 + t] = V[b * 160 + sel_s * 16 + t];
    }
}

// ---------- decoder layer 1 (gathered 16 rows) ----------
__global__ __launch_bounds__(256) void dec1_k(const float* __restrict__ w1,
                                              const float* __restrict__ b1,
                                              const float* __restrict__ vsel,
                                              const int* __restrict__ sel,
                                              float* __restrict__ h1d) {
    const int bx = blockIdx.x;
    const int b = bx >> 1;
    const int col = ((bx & 1) << 8) + threadIdx.x;
    const int s = sel[b];
    float acc = b1[col];
    const float* wrow = w1 + (size_t)(s * 16) * 512 + col;
#pragma unroll
    for (int j = 0; j < 16; ++j) acc = fmaf(vsel[b * 16 + j], wrow[j * 512], acc);
    h1d[(size_t)b * 512 + col] = fmaxf(acc, 0.f);
}

// ---------- generic small fp32 GEMM + act (M=256 fixed) ----------
template <int ACT>
__global__ __launch_bounds__(256) void mlp_k(const float* __restrict__ A,
                                             const float* __restrict__ Bm,
                                             const float* __restrict__ bias,
                                             float* __restrict__ C, int N, int K) {
    __shared__ float As[64 * 16];
    __shared__ float Bs[16 * 64];
    const int t = threadIdx.x;
    const int tx = t & 15, ty = t >> 4;
    const int m0 = blockIdx.y * 64, n0 = blockIdx.x * 64;
    float acc[4][4] = {};
    const int arow = t >> 2, ac4 = (t & 3) * 4;
    const int brow = t >> 4, bc4 = (t & 15) * 4;
    for (int k0 = 0; k0 < K; k0 += 16) {
        __syncthreads();
        *(float4*)&As[arow * 16 + ac4] = *(const float4*)&A[(size_t)(m0 + arow) * K + k0 + ac4];
        float4 bv = {0.f, 0.f, 0.f, 0.f};
        const int bn = n0 + bc4;
        if (bn + 3 < N) bv = *(const float4*)&Bm[(size_t)(k0 + brow) * N + bn];
        *(float4*)&Bs[brow * 64 + bc4] = bv;
        __syncthreads();
#pragma unroll
        for (int k = 0; k < 16; ++k) {
            float av[4], bvv[4];
#pragma unroll
            for (int r = 0; r < 4; ++r) av[r] = As[(ty * 4 + r) * 16 + k];
#pragma unroll
            for (int c = 0; c < 4; ++c) bvv[c] = Bs[k * 64 + tx * 4 + c];
#pragma unroll
            for (int r = 0; r < 4; ++r)
#pragma unroll
                for (int c = 0; c < 4; ++c) acc[r][c] = fmaf(av[r], bvv[c], acc[r][c]);
        }
    }
#pragma unroll
    for (int r = 0; r < 4; ++r) {
        const int m = m0 + ty * 4 + r;
#pragma unroll
        for (int c = 0; c < 4; ++c) {
            const int n = n0 + tx * 4 + c;
            if (n < N) {
                float v = acc[r][c] + bias[n];
                if (ACT == 0) v = fmaxf(v, 0.f);
                else v = 1.f / (1.f + expf(-v));
                C[(size_t)m * N + n] = v;
            }
        }
    }
}

// ---------- launcher ----------
extern "C" void kernel_launch(void* const* d_in, const int* in_sizes, int n_in,
                              void* d_out, int out_size, void* d_ws, size_t ws_size,
                              hipStream_t stream) {
    const float* x   = (const float*)d_in[0];
    const float* w1  = (const float*)d_in[1];
    const float* b1  = (const float*)d_in[2];
    const float* w2  = (const float*)d_in[3];
    const float* b2  = (const float*)d_in[4];
    const float* Wc  = (const float*)d_in[5];
    const float* dw1 = (const float*)d_in[6];
    const float* db1 = (const float*)d_in[7];
    const float* dw2 = (const float*)d_in[8];
    const float* db2 = (const float*)d_in[9];
    const float* dw3 = (const float*)d_in[10];
    const float* db3 = (const float*)d_in[11];
    float* out = (float*)d_out;

    char* ws = (char*)d_ws;
    // region A: conv staging (dead after squash_u_k), then reused by UHAT
    unsigned short* H1T  = (unsigned short*)(ws + 0);          // 52,428,800 B
    unsigned short* W2T  = (unsigned short*)(ws + 52428800);   // 10,616,832 B
    float*          PART = (float*)(ws + 63045632);            // 37,748,736 B
    unsigned short* UHAT = (unsigned short*)(ws + 0);          // 94,371,840 B (aliases region A)
    float* U    = (float*)(ws + 100794368);                    //  9,437,184 B (dead after uhat_k)
    // routing state aliases the dead U region + PART tail:
    float* BL   = (float*)(ws + 94371840);                     // 11,796,480 B
    float* S012 = (float*)(ws + 106168320);                    //    491,520 B (3 x 40960 f32)
    float* V    = (float*)(ws + 106659840);                    //    163,840 B
    int*   SEL  = (int*)(ws + 110231552);
    float* VSEL = (float*)(ws + 110232576);
    float* H1D  = (float*)(ws + 110248960);
    float* H2D  = (float*)(ws + 110773248);                    // end 111,821,824

    float* S0 = S012, *S1 = S012 + 40960, *S2 = S012 + 81920;

    conv1_k<<<256, 256, 0, stream>>>(x, w1, b1, H1T);
    w2t_k<<<512, 256, 0, stream>>>(w2, W2T);
    conv2_k<<<dim3(2, 72, 4), 256, 0, stream>>>(H1T, W2T, PART);
    squash_u_k<<<256, 256, 0, stream>>>(PART, b2, U);
    uhat_k<<<1152, 256, 0, stream>>>(Wc, U, UHAT);
    hipMemsetAsync(S012, 0, 3 * 40960 * sizeof(float), stream);
    route_iter0_k<<<dim3(256, 9), 128, 0, stream>>>((const unsigned int*)UHAT, S0);
    squash_v_k<0><<<256, 160, 0, stream>>>(S0, V, nullptr, nullptr, nullptr);
    route_iter_k<1><<<dim3(256, 9), 256, 0, stream>>>(UHAT, V, BL, S1);
    squash_v_k<0><<<256, 160, 0, stream>>>(S1, V, nullptr, nullptr, nullptr);
    route_iter_k<2><<<dim3(256, 9), 256, 0, stream>>>(UHAT, V, BL, S2);
    squash_v_k<1><<<256, 160, 0, stream>>>(S2, V, out, SEL, VSEL);
    dec1_k<<<512, 256, 0, stream>>>(dw1, db1, VSEL, SEL, H1D);
    mlp_k<0><<<dim3(16, 4), 256, 0, stream>>>(H1D, dw2, db2, H2D, 1024, 512);
    mlp_k<1><<<dim3(13, 4), 256, 0, stream>>>(H2D, dw3, db3, out + 2560, 784, 1024);
}

// Round 4
// 605.619 us; speedup vs baseline: 1.2464x; 1.2164x over previous
//
#include <hip/hip_runtime.h>
#include <cstdint>
#include <cstddef>

// ---------- types / helpers ----------
typedef __bf16 bf16x8 __attribute__((ext_vector_type(8)));
typedef float  floatx4 __attribute__((ext_vector_type(4)));
typedef unsigned short ushort8 __attribute__((ext_vector_type(8)));
typedef unsigned short ushort4v __attribute__((ext_vector_type(4)));

__device__ __forceinline__ float bf2f(unsigned short u) {
    union { unsigned int u32; float f; } x; x.u32 = ((unsigned int)u) << 16; return x.f;
}
__device__ __forceinline__ float bflo(unsigned int u) {
    union { unsigned int u32; float f; } x; x.u32 = u << 16; return x.f;
}
__device__ __forceinline__ float bfhi(unsigned int u) {
    union { unsigned int u32; float f; } x; x.u32 = u & 0xffff0000u; return x.f;
}
__device__ __forceinline__ unsigned short f2bf(float f) {
    union { float f; unsigned int u; } x; x.f = f;
    unsigned int u = x.u;
    unsigned int r = (u + 0x7fffu + ((u >> 16) & 1u)) >> 16;   // RNE
    return (unsigned short)r;
}

#define GLOBAL_U32 const __attribute__((address_space(1))) unsigned int*
#define LDS_U32 __attribute__((address_space(3))) unsigned int*
__device__ __forceinline__ void async_cp16(const void* g, void* l) {
    __builtin_amdgcn_global_load_lds((GLOBAL_U32)g, (LDS_U32)l, 16, 0, 0);
}

// ---------- conv1: x[256,1,28,28] * w[256,1,9,9] -> h1t bf16 NHWC [b][20][20][256] ----------
__global__ __launch_bounds__(256) void conv1_k(const float* __restrict__ x,
                                               const float* __restrict__ w,
                                               const float* __restrict__ bias,
                                               unsigned short* __restrict__ h1t) {
    const int b = blockIdx.x, t = threadIdx.x;
    __shared__ float xs[784];
    for (int idx = t; idx < 784; idx += 256) xs[idx] = x[b * 784 + idx];
    __syncthreads();
    const float* wr = w + t * 81;   // thread t = output channel t
    const float bv = bias[t];
    for (int oh = 0; oh < 20; ++oh) {
        float acc[20];
#pragma unroll
        for (int ow = 0; ow < 20; ++ow) acc[ow] = bv;
#pragma unroll
        for (int kh = 0; kh < 9; ++kh) {
            float xr[28];
            const float* xrow = &xs[(oh + kh) * 28];
#pragma unroll
            for (int q = 0; q < 7; ++q) *(float4*)&xr[q * 4] = *(const float4*)&xrow[q * 4];
#pragma unroll
            for (int kw = 0; kw < 9; ++kw) {
                const float wv = wr[kh * 9 + kw];
#pragma unroll
                for (int ow = 0; ow < 20; ++ow) acc[ow] = fmaf(xr[ow + kw], wv, acc[ow]);
            }
        }
        unsigned short* orow = h1t + (size_t)((b * 20 + oh) * 20) * 256 + t;
#pragma unroll
        for (int ow = 0; ow < 20; ++ow) orow[ow * 256] = f2bf(acc[ow]);
    }
}

// ---------- w2 transform: OIHW fp32 [oc][ic][81] -> bf16 [oc][tap*256+ic] ----------
__global__ __launch_bounds__(256) void w2t_k(const float* __restrict__ w2,
                                             unsigned short* __restrict__ w2t) {
    const int oc = blockIdx.x >> 1, half = blockIdx.x & 1, t = threadIdx.x;
    __shared__ float ws[10368];                       // 128 ic * 81 taps
    const float* src = w2 + (size_t)oc * 20736 + half * 128 * 81;
    for (int idx = t; idx < 10368; idx += 256) ws[idx] = src[idx];
    __syncthreads();
    unsigned short* dst = w2t + (size_t)oc * 20736 + half * 128;
    for (int idx = t; idx < 10368; idx += 256) {
        const int tap = idx >> 7, icl = idx & 127;
        dst[tap * 256 + icl] = f2bf(ws[icl * 81 + tap]);
    }
}

// ---------- conv2 as implicit GEMM, bf16 MFMA, split-K x8, bank-swizzled LDS ----------
__device__ __forceinline__ int c2_rowbase(int m) {
    const int b = m / 36, sp = m % 36;
    const int oh = sp / 6, ow = sp % 6;
    return (b * 400 + oh * 40 + ow * 2) * 256;        // element offset into h1t
}

__global__ __launch_bounds__(256) void conv2_k(const unsigned short* __restrict__ h1t,
                                               const unsigned short* __restrict__ w2t,
                                               unsigned short* __restrict__ part) {
    const int t = threadIdx.x;
    const int bx = blockIdx.x;                        // 0..1 oc-tile
    const int by = blockIdx.y;                        // 0..71 m-tile
    const int z  = blockIdx.z;                        // 0..7 k-split
    __shared__ unsigned short At[128 * 32];           // m rows
    __shared__ unsigned short Bt[128 * 32];           // oc rows

    // staging: LDS slot s=t (16B units): row=s>>2, lds_chunk=s&3 holds global
    // chunk g = lds_chunk ^ ((row>>1)&3)  -> bank-conflict-free b128 reads.
    const int r0 = t >> 2;
    const int g  = (t & 3) ^ ((t >> 3) & 3);
    const int ra0 = c2_rowbase(by * 128 + r0) + g * 8;
    const int ra1 = c2_rowbase(by * 128 + r0 + 64) + g * 8;
    const int oc0 = bx * 128;
    const int bb0 = (oc0 + r0) * 20736 + g * 8;
    const int bb1 = (oc0 + r0 + 64) * 20736 + g * 8;

    const int lane = t & 63, l15 = lane & 15, quad = lane >> 4;
    const int wave = t >> 6;
    const int wOC = (wave & 1) * 64, wM = (wave >> 1) * 64;

    // loop-invariant fragment LDS offsets (ushort units)
    int aO[4], bO[4];
#pragma unroll
    for (int i = 0; i < 4; ++i) {
        const int R = wOC + i * 16 + l15;             // oc row (A-operand from Bt)
        aO[i] = R * 32 + ((quad ^ ((R >> 1) & 3)) << 3);
    }
#pragma unroll
    for (int j = 0; j < 4; ++j) {
        const int R = wM + j * 16 + l15;              // m row (B-operand from At)
        bO[j] = R * 32 + ((quad ^ ((R >> 1) & 3)) << 3);
    }

    floatx4 acc[4][4];
#pragma unroll
    for (int i = 0; i < 4; ++i)
#pragma unroll
        for (int j = 0; j < 4; ++j) acc[i][j] = (floatx4){0.f, 0.f, 0.f, 0.f};

    // K = 648 chunks of 32; split 8 ways: 81 chunks per z
    const int kc0 = 81 * z, kc1 = kc0 + 81;
    for (int kc = kc0; kc < kc1; ++kc) {
        const int tap = kc >> 3;
        const int kh = tap / 9, kw = tap % 9;
        const int aoff = (kh * 20 + kw) * 256 + ((kc & 7) << 5);
        const int k0 = kc << 5;
        __syncthreads();
        async_cp16(h1t + ra0 + aoff, At + t * 8);
        async_cp16(h1t + ra1 + aoff, At + (t + 256) * 8);
        async_cp16(w2t + bb0 + k0, Bt + t * 8);
        async_cp16(w2t + bb1 + k0, Bt + (t + 256) * 8);
        __syncthreads();
        bf16x8 aF[4], bF[4];
#pragma unroll
        for (int i = 0; i < 4; ++i) aF[i] = *(const bf16x8*)(Bt + aO[i]);
#pragma unroll
        for (int j = 0; j < 4; ++j) bF[j] = *(const bf16x8*)(At + bO[j]);
#pragma unroll
        for (int i = 0; i < 4; ++i)
#pragma unroll
            for (int j = 0; j < 4; ++j)
                acc[i][j] = __builtin_amdgcn_mfma_f32_16x16x32_bf16(aF[i], bF[j], acc[i][j], 0, 0, 0);
    }

    // epilogue: D[reg->oc][lane->m]; pack 4 bf16 along n, store to PART[z][m][n]
    unsigned short* pz = part + (size_t)z * 2359296;
#pragma unroll
    for (int i = 0; i < 4; ++i) {
        const int n0 = oc0 + wOC + i * 16 + quad * 4;
#pragma unroll
        for (int j = 0; j < 4; ++j) {
            const int m = by * 128 + wM + j * 16 + l15;
            ushort4v pk;
#pragma unroll
            for (int r = 0; r < 4; ++r) pk[r] = f2bf(acc[i][j][r]);
            *(ushort4v*)(pz + (size_t)m * 256 + n0) = pk;
        }
    }
}

// ---------- reduce split-K(bf16 x8) + bias + squash(axis=w) -> u[b][1152][8] fp32 ----------
__global__ __launch_bounds__(256) void squash_u_k(const unsigned short* __restrict__ part,
                                                  const float* __restrict__ bias,
                                                  float* __restrict__ u) {
    const int b = blockIdx.x, t = threadIdx.x;
    __shared__ float hs[9216];
    const size_t base = (size_t)b * 9216;
    for (int q = t; q < 4608; q += 256) {
        const int idx = q * 2;
        float v0 = bias[idx & 255], v1 = bias[(idx + 1) & 255];
#pragma unroll
        for (int z = 0; z < 8; ++z) {
            const unsigned int uu = *(const unsigned int*)(part + (size_t)z * 2359296 + base + idx);
            v0 += bflo(uu);
            v1 += bfhi(uu);
        }
        hs[idx] = v0; hs[idx + 1] = v1;
    }
    __syncthreads();
    for (int gq = t; gq < 1536; gq += 256) {          // groups (c, oh), squash over ow(6)
        const int c = gq / 6, oh = gq % 6;
        float s[6], sq = 0.f;
#pragma unroll
        for (int ow = 0; ow < 6; ++ow) { s[ow] = hs[(oh * 6 + ow) * 256 + c]; sq = fmaf(s[ow], s[ow], sq); }
        const float norm = sqrtf(sq);
        const float f = (sq / (1.0f + sq)) / (norm + 1e-7f);
        float* up = u + base + c * 36 + oh * 6;
#pragma unroll
        for (int ow = 0; ow < 6; ++ow) up[ow] = s[ow] * f;
    }
}

// ---------- u_hat[b][i][o*16+d] bf16 = sum_e W[o,i,d,e]*u[b,i,e] ----------
__global__ __launch_bounds__(256) void uhat_k(const float* __restrict__ Wc,
                                              const float* __restrict__ u,
                                              unsigned short* __restrict__ uhat) {
    const int i = blockIdx.x, t = threadIdx.x;       // t = b
    __shared__ float Wl[1280];                       // [o][d*8+e]
    __shared__ unsigned short Ul[128 * 168];         // padded transpose buffer (43 KB)
    for (int idx = t; idx < 1280; idx += 256) {
        const int o = idx >> 7, r = idx & 127;
        Wl[idx] = Wc[((size_t)o * 1152 + i) * 128 + r];
    }
    float ur[8];
    *(float4*)&ur[0] = *(const float4*)(u + (size_t)t * 9216 + i * 8);
    *(float4*)&ur[4] = *(const float4*)(u + (size_t)t * 9216 + i * 8 + 4);
    __syncthreads();
    unsigned short val[160];
#pragma unroll 1
    for (int o = 0; o < 10; ++o) {
#pragma unroll
        for (int d = 0; d < 16; ++d) {
            const float* wp = &Wl[o * 128 + d * 8];
            float a = 0.f;
#pragma unroll
            for (int e = 0; e < 8; ++e) a = fmaf(wp[e], ur[e], a);
            val[o * 16 + d] = f2bf(a);
        }
    }
#pragma unroll 1
    for (int h = 0; h < 2; ++h) {
        __syncthreads();
        if ((t >> 7) == h) {
            unsigned short* row = &Ul[(t & 127) * 168];
#pragma unroll
            for (int q = 0; q < 20; ++q) *(ushort8*)(row + q * 8) = *(const ushort8*)(val + q * 8);
        }
        __syncthreads();
        for (int idx = t; idx < 2560; idx += 256) {
            const int r = idx / 20, q = idx % 20;
            const int b = h * 128 + r;
            *(ushort8*)(uhat + ((size_t)b * 1152 + i) * 160 + q * 8) =
                *(const ushort8*)(&Ul[r * 168 + q * 8]);
        }
    }
}

// ---------- routing iteration 0: S0[b][160] = 0.1 * sum_i u_hat ----------
__global__ __launch_bounds__(256) void route_iter0_k(const unsigned int* __restrict__ uhat32,
                                                     float* __restrict__ S0) {
    const int b = blockIdx.x, i0 = blockIdx.y * 128, t = threadIdx.x;
    const int th = t & 127, hi = t >> 7;
    if (th >= 80) return;
    const unsigned int* p = uhat32 + ((size_t)b * 1152 + i0 + hi * 64) * 80 + th;
    float ax = 0.f, ay = 0.f;
#pragma unroll 8
    for (int i = 0; i < 64; ++i) {
        const unsigned int uu = p[i * 80];
        ax += bflo(uu);
        ay += bfhi(uu);
    }
    atomicAdd(&S0[b * 160 + 2 * th], 0.1f * ax);
    atomicAdd(&S0[b * 160 + 2 * th + 1], 0.1f * ay);
}

// ---------- fused routing iteration: logit update + softmax + weighted sum ----------
template <int ITER>
__global__ __launch_bounds__(256) void route_iter_k(const unsigned short* __restrict__ uhat,
                                                    const float* __restrict__ V,
                                                    float* __restrict__ BL,
                                                    float* __restrict__ S) {
    const int b = blockIdx.x, i0 = blockIdx.y * 128, t = threadIdx.x;
    __shared__ __align__(16) unsigned short Ul[128 * 160];   // 40960 B
    __shared__ float cT[10 * 132];
    __shared__ float dots[128 * 10];

    const char* gsrc = (const char*)(uhat + ((size_t)b * 1152 + i0) * 160);
#pragma unroll
    for (int rep = 0; rep < 10; ++rep)
        async_cp16(gsrc + rep * 4096 + t * 16, (char*)Ul + rep * 4096 + t * 16);

    // p1a mapping: o = t%10 fixed per thread, strip s = t/10 (250 active)
    const int o = t % 10, s = t / 10;
    float vr[16];
    if (t < 250) {
#pragma unroll
        for (int q = 0; q < 4; ++q)
            *(float4*)&vr[q * 4] = *(const float4*)(V + b * 160 + o * 16 + q * 4);
    }
    __syncthreads();

    // p1a: dots[i][o] = sum_d u_hat[i,o,d] * v[o,d]
    if (t < 250) {
#pragma unroll
        for (int rep = 0; rep < 6; ++rep) {
            const int i = s + 25 * rep;
            if (i < 128) {
                const ushort8 ua = *(const ushort8*)(Ul + i * 160 + o * 16);
                const ushort8 ub = *(const ushort8*)(Ul + i * 160 + o * 16 + 8);
                float dot = 0.f;
#pragma unroll
                for (int d = 0; d < 8; ++d) dot = fmaf(bf2f(ua[d]), vr[d], dot);
#pragma unroll
                for (int d = 0; d < 8; ++d) dot = fmaf(bf2f(ub[d]), vr[8 + d], dot);
                dots[i * 10 + o] = dot;
            }
        }
    }
    __syncthreads();

    // p1b: per-i logits + softmax -> cT[o][i]
    if (t < 128) {
        float bl[10];
#pragma unroll
        for (int oo = 0; oo < 10; ++oo) bl[oo] = dots[t * 10 + oo];
        if (ITER == 2) {
#pragma unroll
            for (int oo = 0; oo < 10; ++oo) bl[oo] += BL[(size_t)b * 11520 + oo * 1152 + i0 + t];
        } else {
#pragma unroll
            for (int oo = 0; oo < 10; ++oo) BL[(size_t)b * 11520 + oo * 1152 + i0 + t] = bl[oo];
        }
        float mx = bl[0];
#pragma unroll
        for (int oo = 1; oo < 10; ++oo) mx = fmaxf(mx, bl[oo]);
        float ex[10], sum = 0.f;
#pragma unroll
        for (int oo = 0; oo < 10; ++oo) { ex[oo] = expf(bl[oo] - mx); sum += ex[oo]; }
        const float inv = 1.f / sum;
#pragma unroll
        for (int oo = 0; oo < 10; ++oo) cT[oo * 132 + t] = ex[oo] * inv;
    }
    __syncthreads();

    // p2: S[b][160] += sum_i c[i][o] * u_hat[i][od]  (two 64-i halves)
    const int th = t & 127, hi = t >> 7;
    if (th < 80) {
        const int o8 = th >> 3;
        const unsigned int* base = (const unsigned int*)Ul + (size_t)hi * 64 * 80 + th;
        const float* cb = &cT[o8 * 132 + hi * 64];
        float ax = 0.f, ay = 0.f;
#pragma unroll 4
        for (int ii = 0; ii < 64; ++ii) {
            const float c = cb[ii];
            const unsigned int uu = base[ii * 80];
            ax = fmaf(c, bflo(uu), ax);
            ay = fmaf(c, bfhi(uu), ay);
        }
        atomicAdd(&S[b * 160 + 2 * th], ax);
        atomicAdd(&S[b * 160 + 2 * th + 1], ay);
    }
}

// ---------- squash S -> V (+ final: lengths, argmax, vsel) ----------
template <int FINAL>
__global__ __launch_bounds__(160) void squash_v_k(const float* __restrict__ S,
                                                  float* __restrict__ V,
                                                  float* __restrict__ out_len,
                                                  int* __restrict__ sel,
                                                  float* __restrict__ vsel) {
    const int b = blockIdx.x, t = threadIdx.x, o = t >> 4;
    __shared__ float len_s[10];
    __shared__ int sel_s;
    const float x = S[b * 160 + t];
    float sq = x * x;
    sq += __shfl_xor(sq, 1, 16);
    sq += __shfl_xor(sq, 2, 16);
    sq += __shfl_xor(sq, 4, 16);
    sq += __shfl_xor(sq, 8, 16);
    const float norm = sqrtf(sq);
    const float f = (sq / (1.f + sq)) / (norm + 1e-7f);
    V[b * 160 + t] = x * f;
    if (FINAL) {
        if ((t & 15) == 0) {
            const float len = f * norm;
            len_s[o] = len;
            out_len[b * 10 + o] = len;
        }
        __syncthreads();
        if (t == 0) {
            float best = len_s[0]; int bi = 0;
            for (int oo = 1; oo < 10; ++oo) if (len_s[oo] > best) { best = len_s[oo]; bi = oo; }
            sel_s = bi; sel[b] = bi;
        }
        __syncthreads();
        if (t < 16) vsel[b * 16 + t] = V[b * 160 + sel_s * 16 + t];
    }
}

// ---------- decoder layer 1 (gathered 16 rows) ----------
__global__ __launch_bounds__(256) void dec1_k(const float* __restrict__ w1,
                                              const float* __restrict__ b1,
                                              const float* __restrict__ vsel,
                                              const int* __restrict__ sel,
                                              float* __restrict__ h1d) {
    const int bx = blockIdx.x;
    const int b = bx >> 1;
    const int col = ((bx & 1) << 8) + threadIdx.x;
    const int s = sel[b];
    float acc = b1[col];
    const float* wrow = w1 + (size_t)(s * 16) * 512 + col;
#pragma unroll
    for (int j = 0; j < 16; ++j) acc = fmaf(vsel[b * 16 + j], wrow[j * 512], acc);
    h1d[(size_t)b * 512 + col] = fmaxf(acc, 0.f);
}

// ---------- generic small fp32 GEMM + act (M=256 fixed) ----------
template <int ACT>
__global__ __launch_bounds__(256) void mlp_k(const float* __restrict__ A,
                                             const float* __restrict__ Bm,
                                             const float* __restrict__ bias,
                                             float* __restrict__ C, int N, int K) {
    __shared__ float As[64 * 16];
    __shared__ float Bs[16 * 64];
    const int t = threadIdx.x;
    const int tx = t & 15, ty = t >> 4;
    const int m0 = blockIdx.y * 64, n0 = blockIdx.x * 64;
    float acc[4][4] = {};
    const int arow = t >> 2, ac4 = (t & 3) * 4;
    const int brow = t >> 4, bc4 = (t & 15) * 4;
    for (int k0 = 0; k0 < K; k0 += 16) {
        __syncthreads();
        *(float4*)&As[arow * 16 + ac4] = *(const float4*)&A[(size_t)(m0 + arow) * K + k0 + ac4];
        float4 bv = {0.f, 0.f, 0.f, 0.f};
        const int bn = n0 + bc4;
        if (bn + 3 < N) bv = *(const float4*)&Bm[(size_t)(k0 + brow) * N + bn];
        *(float4*)&Bs[brow * 64 + bc4] = bv;
        __syncthreads();
#pragma unroll
        for (int k = 0; k < 16; ++k) {
            float av[4], bvv[4];
#pragma unroll
            for (int r = 0; r < 4; ++r) av[r] = As[(ty * 4 + r) * 16 + k];
#pragma unroll
            for (int c = 0; c < 4; ++c) bvv[c] = Bs[k * 64 + tx * 4 + c];
#pragma unroll
            for (int r = 0; r < 4; ++r)
#pragma unroll
                for (int c = 0; c < 4; ++c) acc[r][c] = fmaf(av[r], bvv[c], acc[r][c]);
        }
    }
#pragma unroll
    for (int r = 0; r < 4; ++r) {
        const int m = m0 + ty * 4 + r;
#pragma unroll
        for (int c = 0; c < 4; ++c) {
            const int n = n0 + tx * 4 + c;
            if (n < N) {
                float v = acc[r][c] + bias[n];
                if (ACT == 0) v = fmaxf(v, 0.f);
                else v = 1.f / (1.f + expf(-v));
                C[(size_t)m * N + n] = v;
            }
        }
    }
}

// ---------- launcher ----------
extern "C" void kernel_launch(void* const* d_in, const int* in_sizes, int n_in,
                              void* d_out, int out_size, void* d_ws, size_t ws_size,
                              hipStream_t stream) {
    const float* x   = (const float*)d_in[0];
    const float* w1  = (const float*)d_in[1];
    const float* b1  = (const float*)d_in[2];
    const float* w2  = (const float*)d_in[3];
    const float* b2  = (const float*)d_in[4];
    const float* Wc  = (const float*)d_in[5];
    const float* dw1 = (const float*)d_in[6];
    const float* db1 = (const float*)d_in[7];
    const float* dw2 = (const float*)d_in[8];
    const float* db2 = (const float*)d_in[9];
    const float* dw3 = (const float*)d_in[10];
    const float* db3 = (const float*)d_in[11];
    float* out = (float*)d_out;

    char* ws = (char*)d_ws;
    // region A: conv staging (dead after squash_u_k), then reused by UHAT
    unsigned short* H1T  = (unsigned short*)(ws + 0);          // 52,428,800 B
    unsigned short* W2T  = (unsigned short*)(ws + 52428800);   // 10,616,832 B
    unsigned short* PART = (unsigned short*)(ws + 63045632);   // 37,748,736 B (bf16, z=8)
    unsigned short* UHAT = (unsigned short*)(ws + 0);          // 94,371,840 B (aliases region A)
    float* U    = (float*)(ws + 100794368);                    //  9,437,184 B (dead after uhat_k)
    float* BL   = (float*)(ws + 94371840);                     // 11,796,480 B (overlaps dead U/PART tail)
    float* S012 = (float*)(ws + 106168320);                    //    491,520 B (3 x 40960 f32)
    float* V    = (float*)(ws + 106659840);                    //    163,840 B
    int*   SEL  = (int*)(ws + 110231552);
    float* VSEL = (float*)(ws + 110232576);
    float* H1D  = (float*)(ws + 110248960);
    float* H2D  = (float*)(ws + 110773248);                    // end 111,821,824

    float* S0 = S012, *S1 = S012 + 40960, *S2 = S012 + 81920;

    conv1_k<<<256, 256, 0, stream>>>(x, w1, b1, H1T);
    w2t_k<<<512, 256, 0, stream>>>(w2, W2T);
    conv2_k<<<dim3(2, 72, 8), 256, 0, stream>>>(H1T, W2T, PART);
    squash_u_k<<<256, 256, 0, stream>>>(PART, b2, U);
    uhat_k<<<1152, 256, 0, stream>>>(Wc, U, UHAT);
    hipMemsetAsync(S012, 0, 3 * 40960 * sizeof(float), stream);
    route_iter0_k<<<dim3(256, 9), 256, 0, stream>>>((const unsigned int*)UHAT, S0);
    squash_v_k<0><<<256, 160, 0, stream>>>(S0, V, nullptr, nullptr, nullptr);
    route_iter_k<1><<<dim3(256, 9), 256, 0, stream>>>(UHAT, V, BL, S1);
    squash_v_k<0><<<256, 160, 0, stream>>>(S1, V, nullptr, nullptr, nullptr);
    route_iter_k<2><<<dim3(256, 9), 256, 0, stream>>>(UHAT, V, BL, S2);
    squash_v_k<1><<<256, 160, 0, stream>>>(S2, V, out, SEL, VSEL);
    dec1_k<<<512, 256, 0, stream>>>(dw1, db1, VSEL, SEL, H1D);
    mlp_k<0><<<dim3(16, 4), 256, 0, stream>>>(H1D, dw2, db2, H2D, 1024, 512);
    mlp_k<1><<<dim3(13, 4), 256, 0, stream>>>(H2D, dw3, db3, out + 2560, 784, 1024);
}

// Round 5
// 572.086 us; speedup vs baseline: 1.3195x; 1.0586x over previous
//
#include <hip/hip_runtime.h>
#include <cstdint>
#include <cstddef>

// ---------- types / helpers ----------
typedef __bf16 bf16x8 __attribute__((ext_vector_type(8)));
typedef float  floatx4 __attribute__((ext_vector_type(4)));
typedef unsigned short ushort8 __attribute__((ext_vector_type(8)));
typedef unsigned short ushort4v __attribute__((ext_vector_type(4)));

__device__ __forceinline__ float bf2f(unsigned short u) {
    union { unsigned int u32; float f; } x; x.u32 = ((unsigned int)u) << 16; return x.f;
}
__device__ __forceinline__ float bflo(unsigned int u) {
    union { unsigned int u32; float f; } x; x.u32 = u << 16; return x.f;
}
__device__ __forceinline__ float bfhi(unsigned int u) {
    union { unsigned int u32; float f; } x; x.u32 = u & 0xffff0000u; return x.f;
}
__device__ __forceinline__ unsigned short f2bf(float f) {
    union { float f; unsigned int u; } x; x.f = f;
    unsigned int u = x.u;
    unsigned int r = (u + 0x7fffu + ((u >> 16) & 1u)) >> 16;   // RNE
    return (unsigned short)r;
}

#define GLOBAL_U32 const __attribute__((address_space(1))) unsigned int*
#define LDS_U32 __attribute__((address_space(3))) unsigned int*
__device__ __forceinline__ void async_cp16(const void* g, void* l) {
    __builtin_amdgcn_global_load_lds((GLOBAL_U32)g, (LDS_U32)l, 16, 0, 0);
}

// ---------- conv1: x[256,1,28,28] * w[256,1,9,9] -> h1t bf16 NHWC [b][20][20][256] ----------
__global__ __launch_bounds__(256) void conv1_k(const float* __restrict__ x,
                                               const float* __restrict__ w,
                                               const float* __restrict__ bias,
                                               unsigned short* __restrict__ h1t) {
    const int b = blockIdx.x, t = threadIdx.x;
    __shared__ float xs[784];
    for (int idx = t; idx < 784; idx += 256) xs[idx] = x[b * 784 + idx];
    __syncthreads();
    const float* wr = w + t * 81;   // thread t = output channel t
    const float bv = bias[t];
    for (int oh = 0; oh < 20; ++oh) {
        float acc[20];
#pragma unroll
        for (int ow = 0; ow < 20; ++ow) acc[ow] = bv;
#pragma unroll
        for (int kh = 0; kh < 9; ++kh) {
            float xr[28];
            const float* xrow = &xs[(oh + kh) * 28];
#pragma unroll
            for (int q = 0; q < 7; ++q) *(float4*)&xr[q * 4] = *(const float4*)&xrow[q * 4];
#pragma unroll
            for (int kw = 0; kw < 9; ++kw) {
                const float wv = wr[kh * 9 + kw];
#pragma unroll
                for (int ow = 0; ow < 20; ++ow) acc[ow] = fmaf(xr[ow + kw], wv, acc[ow]);
            }
        }
        unsigned short* orow = h1t + (size_t)((b * 20 + oh) * 20) * 256 + t;
#pragma unroll
        for (int ow = 0; ow < 20; ++ow) orow[ow * 256] = f2bf(acc[ow]);
    }
}

// ---------- w2 transform: OIHW fp32 [oc][ic][81] -> bf16 [oc][tap*256+ic] ----------
__global__ __launch_bounds__(256) void w2t_k(const float* __restrict__ w2,
                                             unsigned short* __restrict__ w2t) {
    const int oc = blockIdx.x >> 1, half = blockIdx.x & 1, t = threadIdx.x;
    __shared__ float ws[10368];                       // 128 ic * 81 taps
    const float* src = w2 + (size_t)oc * 20736 + half * 128 * 81;
    for (int idx = t; idx < 10368; idx += 256) ws[idx] = src[idx];
    __syncthreads();
    unsigned short* dst = w2t + (size_t)oc * 20736 + half * 128;
    for (int idx = t; idx < 10368; idx += 256) {
        const int tap = idx >> 7, icl = idx & 127;
        dst[tap * 256 + icl] = f2bf(ws[icl * 81 + tap]);
    }
}

// ---------- conv2 as implicit GEMM, bf16 MFMA, split-K x8, BK=64, swizzled LDS ----------
__device__ __forceinline__ int c2_rowbase(int m) {
    const int b = m / 36, sp = m % 36;
    const int oh = sp / 6, ow = sp % 6;
    return (b * 400 + oh * 40 + ow * 2) * 256;        // element offset into h1t
}

__global__ __launch_bounds__(256) void conv2_k(const unsigned short* __restrict__ h1t,
                                               const unsigned short* __restrict__ w2t,
                                               unsigned short* __restrict__ part) {
    const int t = threadIdx.x;
    const int bx = blockIdx.x;                        // 0..1 oc-tile
    const int by = blockIdx.y;                        // 0..71 m-tile
    const int z  = blockIdx.z;                        // 0..7 k-split (pair-granular)
    __shared__ unsigned short At[128 * 64];           // m rows, 64 bf16 (K-pair)
    __shared__ unsigned short Bt[128 * 64];           // oc rows

    const int oc0 = bx * 128;

    // staging: each thread stages 4 A-units and 4 B-units (16B each).
    // LDS slot a = t + 256*k (lane-contiguous per wave); row = a>>3, phys slot
    // s = a&7 holds logical unit u = s ^ (row&7)  (bank-conflict-free b128 reads).
    int aRB[4], aCU[4], bBase[4];
#pragma unroll
    for (int k = 0; k < 4; ++k) {
        const int a = t + 256 * k;
        const int r = a >> 3, s = a & 7;
        const int u = s ^ (r & 7);
        aRB[k] = c2_rowbase(by * 128 + r) + (u & 3) * 8;
        aCU[k] = u >> 2;                              // which chunk of the pair
        bBase[k] = (oc0 + r) * 20736 + (u >> 2) * 32 + (u & 3) * 8;
    }

    const int lane = t & 63, l15 = lane & 15, quad = lane >> 4;
    const int wave = t >> 6;
    const int wOC = (wave & 1) * 64, wM = (wave >> 1) * 64;

    // fragment LDS offsets (ushort units): row stride 64, unit u = h*4+quad
    int aO[2][4], bO[2][4];
#pragma unroll
    for (int i = 0; i < 4; ++i) {
        const int R = wOC + i * 16 + l15;             // oc row (A-operand from Bt)
#pragma unroll
        for (int h = 0; h < 2; ++h)
            aO[h][i] = R * 64 + (((h * 4 + quad) ^ (R & 7)) << 3);
    }
#pragma unroll
    for (int j = 0; j < 4; ++j) {
        const int R = wM + j * 16 + l15;              // m row (B-operand from At)
#pragma unroll
        for (int h = 0; h < 2; ++h)
            bO[h][j] = R * 64 + (((h * 4 + quad) ^ (R & 7)) << 3);
    }

    floatx4 acc[4][4];
#pragma unroll
    for (int i = 0; i < 4; ++i)
#pragma unroll
        for (int j = 0; j < 4; ++j) acc[i][j] = (floatx4){0.f, 0.f, 0.f, 0.f};

    // K = 648 chunks = 324 pairs; z covers pairs [p0,p1)
    const int p0 = (324 * z) >> 3, p1 = (324 * (z + 1)) >> 3;
    for (int p = p0; p < p1; ++p) {
        const int tap = p >> 2;                       // both chunks of a pair share tap
        const int kh = tap / 9, kw = tap - 9 * kh;
        const int aoffB = (kh * 20 + kw) * 256;
        const int ce7 = (2 * p) & 7;
        __syncthreads();
#pragma unroll
        for (int k = 0; k < 4; ++k)
            async_cp16(h1t + aRB[k] + aoffB + (ce7 + aCU[k]) * 32, At + (t + 256 * k) * 8);
#pragma unroll
        for (int k = 0; k < 4; ++k)
            async_cp16(w2t + bBase[k] + p * 64, Bt + (t + 256 * k) * 8);
        __syncthreads();
#pragma unroll
        for (int h = 0; h < 2; ++h) {
            bf16x8 aF[4], bF[4];
#pragma unroll
            for (int i = 0; i < 4; ++i) aF[i] = *(const bf16x8*)(Bt + aO[h][i]);
#pragma unroll
            for (int j = 0; j < 4; ++j) bF[j] = *(const bf16x8*)(At + bO[h][j]);
#pragma unroll
            for (int i = 0; i < 4; ++i)
#pragma unroll
                for (int j = 0; j < 4; ++j)
                    acc[i][j] = __builtin_amdgcn_mfma_f32_16x16x32_bf16(aF[i], bF[j], acc[i][j], 0, 0, 0);
        }
    }

    // epilogue: D[reg->oc][lane->m]; pack 4 bf16 along n, store to PART[z][m][n]
    unsigned short* pz = part + (size_t)z * 2359296;
#pragma unroll
    for (int i = 0; i < 4; ++i) {
        const int n0 = oc0 + wOC + i * 16 + quad * 4;
#pragma unroll
        for (int j = 0; j < 4; ++j) {
            const int m = by * 128 + wM + j * 16 + l15;
            ushort4v pk;
#pragma unroll
            for (int r = 0; r < 4; ++r) pk[r] = f2bf(acc[i][j][r]);
            *(ushort4v*)(pz + (size_t)m * 256 + n0) = pk;
        }
    }
}

// ---------- reduce split-K(bf16 x8) + bias + squash(axis=w) -> u[b][1152][8] fp32 ----------
__global__ __launch_bounds__(256) void squash_u_k(const unsigned short* __restrict__ part,
                                                  const float* __restrict__ bias,
                                                  float* __restrict__ u) {
    const int b = blockIdx.x, t = threadIdx.x;
    __shared__ float hs[9216];
    const size_t base = (size_t)b * 9216;
    for (int q = t; q < 4608; q += 256) {
        const int idx = q * 2;
        float v0 = bias[idx & 255], v1 = bias[(idx + 1) & 255];
#pragma unroll
        for (int z = 0; z < 8; ++z) {
            const unsigned int uu = *(const unsigned int*)(part + (size_t)z * 2359296 + base + idx);
            v0 += bflo(uu);
            v1 += bfhi(uu);
        }
        hs[idx] = v0; hs[idx + 1] = v1;
    }
    __syncthreads();
    for (int gq = t; gq < 1536; gq += 256) {          // groups (c, oh), squash over ow(6)
        const int c = gq / 6, oh = gq % 6;
        float s[6], sq = 0.f;
#pragma unroll
        for (int ow = 0; ow < 6; ++ow) { s[ow] = hs[(oh * 6 + ow) * 256 + c]; sq = fmaf(s[ow], s[ow], sq); }
        const float norm = sqrtf(sq);
        const float f = (sq / (1.0f + sq)) / (norm + 1e-7f);
        float* up = u + base + c * 36 + oh * 6;
#pragma unroll
        for (int ow = 0; ow < 6; ++ow) up[ow] = s[ow] * f;
    }
}

// ---------- u_hat[b][i][o*16+d] bf16 = sum_e W[o,i,d,e]*u[b,i,e] ----------
__global__ __launch_bounds__(256) void uhat_k(const float* __restrict__ Wc,
                                              const float* __restrict__ u,
                                              unsigned short* __restrict__ uhat) {
    const int i = blockIdx.x, t = threadIdx.x;       // t = b
    __shared__ float Wl[1280];                       // [o][d*8+e]
    __shared__ unsigned short Ul[128 * 168];         // padded transpose buffer (43 KB)
    for (int idx = t; idx < 1280; idx += 256) {
        const int o = idx >> 7, r = idx & 127;
        Wl[idx] = Wc[((size_t)o * 1152 + i) * 128 + r];
    }
    float ur[8];
    *(float4*)&ur[0] = *(const float4*)(u + (size_t)t * 9216 + i * 8);
    *(float4*)&ur[4] = *(const float4*)(u + (size_t)t * 9216 + i * 8 + 4);
    __syncthreads();
    unsigned short val[160];
#pragma unroll 1
    for (int o = 0; o < 10; ++o) {
#pragma unroll
        for (int d = 0; d < 16; ++d) {
            const float* wp = &Wl[o * 128 + d * 8];
            float a = 0.f;
#pragma unroll
            for (int e = 0; e < 8; ++e) a = fmaf(wp[e], ur[e], a);
            val[o * 16 + d] = f2bf(a);
        }
    }
#pragma unroll 1
    for (int h = 0; h < 2; ++h) {
        __syncthreads();
        if ((t >> 7) == h) {
            unsigned short* row = &Ul[(t & 127) * 168];
#pragma unroll
            for (int q = 0; q < 20; ++q) *(ushort8*)(row + q * 8) = *(const ushort8*)(val + q * 8);
        }
        __syncthreads();
        for (int idx = t; idx < 2560; idx += 256) {
            const int r = idx / 20, q = idx % 20;
            const int b = h * 128 + r;
            *(ushort8*)(uhat + ((size_t)b * 1152 + i) * 160 + q * 8) =
                *(const ushort8*)(&Ul[r * 168 + q * 8]);
        }
    }
}

// ---------- routing iteration 0: S0[b][160] = 0.1 * sum_i u_hat ----------
__global__ __launch_bounds__(256) void route_iter0_k(const unsigned int* __restrict__ uhat32,
                                                     float* __restrict__ S0) {
    const int b = blockIdx.x, i0 = blockIdx.y * 128, t = threadIdx.x;
    const int th = t & 127, hi = t >> 7;
    if (th >= 80) return;
    const unsigned int* p = uhat32 + ((size_t)b * 1152 + i0 + hi * 64) * 80 + th;
    float ax = 0.f, ay = 0.f;
#pragma unroll 8
    for (int i = 0; i < 64; ++i) {
        const unsigned int uu = p[i * 80];
        ax += bflo(uu);
        ay += bfhi(uu);
    }
    atomicAdd(&S0[b * 160 + 2 * th], 0.1f * ax);
    atomicAdd(&S0[b * 160 + 2 * th + 1], 0.1f * ay);
}

// ---------- fused routing iteration: squash(S_in) + logit update + softmax + weighted sum ----------
template <int ITER>
__global__ __launch_bounds__(256) void route_iter_k(const unsigned short* __restrict__ uhat,
                                                    const float* __restrict__ S_in,
                                                    float* __restrict__ BL,
                                                    float* __restrict__ S_out) {
    const int b = blockIdx.x, i0 = blockIdx.y * 128, t = threadIdx.x;
    __shared__ __align__(16) unsigned short Ul[128 * 160];   // 40960 B
    __shared__ float Vl[160];
    __shared__ float cT[10 * 132];
    __shared__ float dots[128 * 10];

    const char* gsrc = (const char*)(uhat + ((size_t)b * 1152 + i0) * 160);
#pragma unroll
    for (int rep = 0; rep < 10; ++rep)
        async_cp16(gsrc + rep * 4096 + t * 16, (char*)Ul + rep * 4096 + t * 16);

    // phase 0: squash S_in -> Vl (redundant per block; 160 floats)
    if (t < 160) {
        const float x = S_in[b * 160 + t];
        float sq = x * x;
        sq += __shfl_xor(sq, 1, 16);
        sq += __shfl_xor(sq, 2, 16);
        sq += __shfl_xor(sq, 4, 16);
        sq += __shfl_xor(sq, 8, 16);
        const float norm = sqrtf(sq);
        const float f = (sq / (1.f + sq)) / (norm + 1e-7f);
        Vl[t] = x * f;
    }
    __syncthreads();                                  // drains async + Vl visible

    // p1a mapping: o = t%10 fixed per thread, strip s = t/10 (250 active)
    const int o = t % 10, s = t / 10;
    float vr[16];
    if (t < 250) {
#pragma unroll
        for (int q = 0; q < 4; ++q)
            *(float4*)&vr[q * 4] = *(const float4*)(&Vl[o * 16 + q * 4]);
    }

    // p1a: dots[i][o] = sum_d u_hat[i,o,d] * v[o,d]
    if (t < 250) {
#pragma unroll
        for (int rep = 0; rep < 6; ++rep) {
            const int i = s + 25 * rep;
            if (i < 128) {
                const ushort8 ua = *(const ushort8*)(Ul + i * 160 + o * 16);
                const ushort8 ub = *(const ushort8*)(Ul + i * 160 + o * 16 + 8);
                float dot = 0.f;
#pragma unroll
                for (int d = 0; d < 8; ++d) dot = fmaf(bf2f(ua[d]), vr[d], dot);
#pragma unroll
                for (int d = 0; d < 8; ++d) dot = fmaf(bf2f(ub[d]), vr[8 + d], dot);
                dots[i * 10 + o] = dot;
            }
        }
    }
    __syncthreads();

    // p1b: per-i logits + softmax -> cT[o][i]
    if (t < 128) {
        float bl[10];
#pragma unroll
        for (int oo = 0; oo < 10; ++oo) bl[oo] = dots[t * 10 + oo];
        if (ITER == 2) {
#pragma unroll
            for (int oo = 0; oo < 10; ++oo) bl[oo] += BL[(size_t)b * 11520 + oo * 1152 + i0 + t];
        } else {
#pragma unroll
            for (int oo = 0; oo < 10; ++oo) BL[(size_t)b * 11520 + oo * 1152 + i0 + t] = bl[oo];
        }
        float mx = bl[0];
#pragma unroll
        for (int oo = 1; oo < 10; ++oo) mx = fmaxf(mx, bl[oo]);
        float ex[10], sum = 0.f;
#pragma unroll
        for (int oo = 0; oo < 10; ++oo) { ex[oo] = expf(bl[oo] - mx); sum += ex[oo]; }
        const float inv = 1.f / sum;
#pragma unroll
        for (int oo = 0; oo < 10; ++oo) cT[oo * 132 + t] = ex[oo] * inv;
    }
    __syncthreads();

    // p2: S_out[b][160] += sum_i c[i][o] * u_hat[i][od]  (two 64-i halves)
    const int th = t & 127, hi = t >> 7;
    if (th < 80) {
        const int o8 = th >> 3;
        const unsigned int* base = (const unsigned int*)Ul + (size_t)hi * 64 * 80 + th;
        const float* cb = &cT[o8 * 132 + hi * 64];
        float ax = 0.f, ay = 0.f;
#pragma unroll 4
        for (int ii = 0; ii < 64; ++ii) {
            const float c = cb[ii];
            const unsigned int uu = base[ii * 80];
            ax = fmaf(c, bflo(uu), ax);
            ay = fmaf(c, bfhi(uu), ay);
        }
        atomicAdd(&S_out[b * 160 + 2 * th], ax);
        atomicAdd(&S_out[b * 160 + 2 * th + 1], ay);
    }
}

// ---------- final: squash S2 -> lengths, argmax, vsel ----------
__global__ __launch_bounds__(160) void final_k(const float* __restrict__ S,
                                               float* __restrict__ out_len,
                                               int* __restrict__ sel,
                                               float* __restrict__ vsel) {
    const int b = blockIdx.x, t = threadIdx.x, o = t >> 4;
    __shared__ float v_s[160];
    __shared__ float len_s[10];
    __shared__ int sel_s;
    const float x = S[b * 160 + t];
    float sq = x * x;
    sq += __shfl_xor(sq, 1, 16);
    sq += __shfl_xor(sq, 2, 16);
    sq += __shfl_xor(sq, 4, 16);
    sq += __shfl_xor(sq, 8, 16);
    const float norm = sqrtf(sq);
    const float f = (sq / (1.f + sq)) / (norm + 1e-7f);
    v_s[t] = x * f;
    if ((t & 15) == 0) {
        const float len = f * norm;
        len_s[o] = len;
        out_len[b * 10 + o] = len;
    }
    __syncthreads();
    if (t == 0) {
        float best = len_s[0]; int bi = 0;
        for (int oo = 1; oo < 10; ++oo) if (len_s[oo] > best) { best = len_s[oo]; bi = oo; }
        sel_s = bi; sel[b] = bi;
    }
    __syncthreads();
    if (t < 16) vsel[b * 16 + t] = v_s[sel_s * 16 + t];
}

// ---------- decoder layer 1 (gathered 16 rows) ----------
__global__ __launch_bounds__(256) void dec1_k(const float* __restrict__ w1,
                                              const float* __restrict__ b1,
                                              const float* __restrict__ vsel,
                                              const int* __restrict__ sel,
                                              float* __restrict__ h1d) {
    const int bx = blockIdx.x;
    const int b = bx >> 1;
    const int col = ((bx & 1) << 8) + threadIdx.x;
    const int s = sel[b];
    float acc = b1[col];
    const float* wrow = w1 + (size_t)(s * 16) * 512 + col;
#pragma unroll
    for (int j = 0; j < 16; ++j) acc = fmaf(vsel[b * 16 + j], wrow[j * 512], acc);
    h1d[(size_t)b * 512 + col] = fmaxf(acc, 0.f);
}

// ---------- generic small fp32 GEMM + act (M=256 fixed) ----------
template <int ACT>
__global__ __launch_bounds__(256) void mlp_k(const float* __restrict__ A,
                                             const float* __restrict__ Bm,
                                             const float* __restrict__ bias,
                                             float* __restrict__ C, int N, int K) {
    __shared__ float As[64 * 16];
    __shared__ float Bs[16 * 64];
    const int t = threadIdx.x;
    const int tx = t & 15, ty = t >> 4;
    const int m0 = blockIdx.y * 64, n0 = blockIdx.x * 64;
    float acc[4][4] = {};
    const int arow = t >> 2, ac4 = (t & 3) * 4;
    const int brow = t >> 4, bc4 = (t & 15) * 4;
    for (int k0 = 0; k0 < K; k0 += 16) {
        __syncthreads();
        *(float4*)&As[arow * 16 + ac4] = *(const float4*)&A[(size_t)(m0 + arow) * K + k0 + ac4];
        float4 bv = {0.f, 0.f, 0.f, 0.f};
        const int bn = n0 + bc4;
        if (bn + 3 < N) bv = *(const float4*)&Bm[(size_t)(k0 + brow) * N + bn];
        *(float4*)&Bs[brow * 64 + bc4] = bv;
        __syncthreads();
#pragma unroll
        for (int k = 0; k < 16; ++k) {
            float av[4], bvv[4];
#pragma unroll
            for (int r = 0; r < 4; ++r) av[r] = As[(ty * 4 + r) * 16 + k];
#pragma unroll
            for (int c = 0; c < 4; ++c) bvv[c] = Bs[k * 64 + tx * 4 + c];
#pragma unroll
            for (int r = 0; r < 4; ++r)
#pragma unroll
                for (int c = 0; c < 4; ++c) acc[r][c] = fmaf(av[r], bvv[c], acc[r][c]);
        }
    }
#pragma unroll
    for (int r = 0; r < 4; ++r) {
        const int m = m0 + ty * 4 + r;
#pragma unroll
        for (int c = 0; c < 4; ++c) {
            const int n = n0 + tx * 4 + c;
            if (n < N) {
                float v = acc[r][c] + bias[n];
                if (ACT == 0) v = fmaxf(v, 0.f);
                else v = 1.f / (1.f + expf(-v));
                C[(size_t)m * N + n] = v;
            }
        }
    }
}

// ---------- launcher ----------
extern "C" void kernel_launch(void* const* d_in, const int* in_sizes, int n_in,
                              void* d_out, int out_size, void* d_ws, size_t ws_size,
                              hipStream_t stream) {
    const float* x   = (const float*)d_in[0];
    const float* w1  = (const float*)d_in[1];
    const float* b1  = (const float*)d_in[2];
    const float* w2  = (const float*)d_in[3];
    const float* b2  = (const float*)d_in[4];
    const float* Wc  = (const float*)d_in[5];
    const float* dw1 = (const float*)d_in[6];
    const float* db1 = (const float*)d_in[7];
    const float* dw2 = (const float*)d_in[8];
    const float* db2 = (const float*)d_in[9];
    const float* dw3 = (const float*)d_in[10];
    const float* db3 = (const float*)d_in[11];
    float* out = (float*)d_out;

    char* ws = (char*)d_ws;
    // region A: conv staging (dead after squash_u_k), then reused by UHAT
    unsigned short* H1T  = (unsigned short*)(ws + 0);          // 52,428,800 B
    unsigned short* W2T  = (unsigned short*)(ws + 52428800);   // 10,616,832 B
    unsigned short* PART = (unsigned short*)(ws + 63045632);   // 37,748,736 B (bf16, z=8)
    unsigned short* UHAT = (unsigned short*)(ws + 0);          // 94,371,840 B (aliases region A)
    float* U    = (float*)(ws + 100794368);                    //  9,437,184 B (dead after uhat_k)
    float* BL   = (float*)(ws + 94371840);                     // 11,796,480 B (alive only during route iters)
    float* S012 = (float*)(ws + 106168320);                    //    491,520 B (3 x 40960 f32)
    int*   SEL  = (int*)(ws + 110231552);
    float* VSEL = (float*)(ws + 110232576);
    float* H1D  = (float*)(ws + 110248960);
    float* H2D  = (float*)(ws + 110773248);                    // end 111,821,824

    float* S0 = S012, *S1 = S012 + 40960, *S2 = S012 + 81920;

    conv1_k<<<256, 256, 0, stream>>>(x, w1, b1, H1T);
    w2t_k<<<512, 256, 0, stream>>>(w2, W2T);
    conv2_k<<<dim3(2, 72, 8), 256, 0, stream>>>(H1T, W2T, PART);
    squash_u_k<<<256, 256, 0, stream>>>(PART, b2, U);
    uhat_k<<<1152, 256, 0, stream>>>(Wc, U, UHAT);
    hipMemsetAsync(S012, 0, 3 * 40960 * sizeof(float), stream);
    route_iter0_k<<<dim3(256, 9), 256, 0, stream>>>((const unsigned int*)UHAT, S0);
    route_iter_k<1><<<dim3(256, 9), 256, 0, stream>>>(UHAT, S0, BL, S1);
    route_iter_k<2><<<dim3(256, 9), 256, 0, stream>>>(UHAT, S1, BL, S2);
    final_k<<<256, 160, 0, stream>>>(S2, out, SEL, VSEL);
    dec1_k<<<512, 256, 0, stream>>>(dw1, db1, VSEL, SEL, H1D);
    mlp_k<0><<<dim3(16, 4), 256, 0, stream>>>(H1D, dw2, db2, H2D, 1024, 512);
    mlp_k<1><<<dim3(13, 4), 256, 0, stream>>>(H2D, dw3, db3, out + 2560, 784, 1024);
}